// Round 5
// baseline (383.657 us; speedup 1.0000x reference)
//
#include <hip/hip_runtime.h>

// 2-layer GCN, CSR-gather formulation (no float atomics).
// Key identity: A_norm·(x@W1) = (A_norm·x)@W1 -> aggregate layer 1 in 12-ch space.
// CSR stores ONLY the 4B source index; norm = dinv[src]*dinv[dst] computed in-gather.

#define IN_CH 12
#define HID 128
#define OUTC 64
#define PADK 132  // A-tile row stride in floats for gemm2 (breaks pow2 bank stride)

__global__ void k_zero_i(int* __restrict__ p, int n) {
    int i = blockIdx.x * blockDim.x + threadIdx.x;
    if (i < n) p[i] = 0;
}

__global__ void k_count(const int* __restrict__ col, int* __restrict__ cnt, int E) {
    int e = blockIdx.x * blockDim.x + threadIdx.x;
    if (e < E) atomicAdd(&cnt[col[e]], 1);
}

// dinv[i]=rsqrt(cnt[i]+1); start[i]=cur[i]=exclusive running offset
__global__ __launch_bounds__(256) void k_alloc(
    const int* __restrict__ cnt, float* __restrict__ dinv,
    int* __restrict__ start, int* __restrict__ cur,
    int* __restrict__ total, int N) {
    __shared__ int sdata[256];
    __shared__ int sbase;
    int i = blockIdx.x * 256 + threadIdx.x;
    int v = (i < N) ? cnt[i] : 0;
    if (i < N) dinv[i] = rsqrtf((float)v + 1.0f);
    sdata[threadIdx.x] = v;
    __syncthreads();
#pragma unroll
    for (int off = 1; off < 256; off <<= 1) {
        int t = (threadIdx.x >= off) ? sdata[threadIdx.x - off] : 0;
        __syncthreads();
        sdata[threadIdx.x] += t;
        __syncthreads();
    }
    if (threadIdx.x == 255) sbase = atomicAdd(total, sdata[255]);
    __syncthreads();
    if (i < N) {
        int s = sbase + sdata[threadIdx.x] - v;  // exclusive scan
        start[i] = s;
        cur[i]   = s;
    }
}

// rs[cur[col]++] = row  (one atomic, one 4B scattered write per edge)
__global__ void k_fill(const int* __restrict__ row, const int* __restrict__ col,
                       int* __restrict__ cur, int* __restrict__ rs, int E) {
    int e = blockIdx.x * blockDim.x + threadIdx.x;
    if (e >= E) return;
    int p = atomicAdd(&cur[col[e]], 1);
    rs[p] = row[e];
}

// aggx[n] = sum_{e->n} x[rs_e]*dinv[rs_e]*dinv[n] + x[n]*dinv[n]^2   (12 channels)
// block = 192 threads = 16 nodes x 12 lanes
__global__ __launch_bounds__(192) void k_gather_x(
    const int* __restrict__ start, const int* __restrict__ cnt,
    const float* __restrict__ dinv, const int* __restrict__ rs,
    const float* __restrict__ x, float* __restrict__ aggx, int N) {
    int ln = threadIdx.x / 12;
    int c  = threadIdx.x % 12;
    int n  = blockIdx.x * 16 + ln;
    if (n >= N) return;
    float dv = dinv[n];
    float acc = x[(size_t)n * IN_CH + c] * dv * dv;
    int s0 = start[n], k = cnt[n];
#pragma unroll 4
    for (int j = 0; j < k; ++j) {
        int r = rs[s0 + j];                       // broadcast within lane-group
        float nrm = dinv[r] * dv;
        acc = fmaf(x[(size_t)r * IN_CH + c], nrm, acc);
    }
    aggx[(size_t)n * IN_CH + c] = acc;
}

// out1 = relu(aggx @ W1 + b1)   (block = 256 threads, 16 nodes x 128 ch)
__global__ __launch_bounds__(256) void k_gemm1b(
    const float* __restrict__ aggx, const float* __restrict__ W1,
    const float* __restrict__ b1, float* __restrict__ out1, int N) {
    __shared__ float w1s[IN_CH * HID];  // 6 KiB
    __shared__ float axs[16][IN_CH];    // 768 B
    for (int i = threadIdx.x; i < IN_CH * HID; i += 256) w1s[i] = W1[i];
    long long base = (long long)blockIdx.x * 16;
    if (threadIdx.x < 16 * IN_CH) {
        int r = threadIdx.x / IN_CH, k = threadIdx.x % IN_CH;
        long long n = base + r;
        axs[r][k] = (n < N) ? aggx[n * IN_CH + k] : 0.0f;
    }
    __syncthreads();
    int c    = threadIdx.x & 127;
    int half = threadIdx.x >> 7;
    float bb = b1[c];
    float acc[8];
#pragma unroll
    for (int j = 0; j < 8; ++j) acc[j] = bb;
#pragma unroll
    for (int k = 0; k < IN_CH; ++k) {
        float w = w1s[k * HID + c];
#pragma unroll
        for (int j = 0; j < 8; ++j)
            acc[j] = fmaf(axs[half * 8 + j][k], w, acc[j]);
    }
#pragma unroll
    for (int j = 0; j < 8; ++j) {
        long long n = base + half * 8 + j;
        if (n < N) out1[n * HID + c] = fmaxf(acc[j], 0.0f);
    }
}

// h2 = out1 @ W2 : LDS-tiled GEMM, 64x64 tile, 4x4 register tile per thread
__global__ __launch_bounds__(256) void k_gemm2(
    const float* __restrict__ out1, const float* __restrict__ W2,
    float* __restrict__ h2, int N) {
    __shared__ float as[64 * PADK];   // 33.8 KiB
    __shared__ float ws[HID * OUTC];  // 32 KiB
    for (int i = threadIdx.x; i < (HID * OUTC) / 4; i += 256)
        ((float4*)ws)[i] = ((const float4*)W2)[i];
    long long base = (long long)blockIdx.x * 64;
    for (int i = threadIdx.x; i < 2048; i += 256) {
        int r = i >> 5, kq = i & 31;
        long long rr = base + r; if (rr >= N) rr = N - 1;
        float4 v = ((const float4*)(out1 + rr * HID))[kq];
        *(float4*)(as + r * PADK + 4 * kq) = v;
    }
    __syncthreads();
    int tc = threadIdx.x & 15;
    int tr = threadIdx.x >> 4;
    float acc[4][4] = {};
    const float* ar = as + 4 * tr * PADK;
#pragma unroll 8
    for (int k = 0; k < HID; k += 4) {
        float4 a[4], w[4];
#pragma unroll
        for (int j = 0; j < 4; ++j) a[j] = *(const float4*)(ar + j * PADK + k);
#pragma unroll
        for (int kk = 0; kk < 4; ++kk) w[kk] = *(const float4*)(ws + (k + kk) * OUTC + 4 * tc);
#pragma unroll
        for (int kk = 0; kk < 4; ++kk) {
            float aw[4] = {w[kk].x, w[kk].y, w[kk].z, w[kk].w};
#pragma unroll
            for (int j = 0; j < 4; ++j) {
                float av = (kk == 0) ? a[j].x : (kk == 1) ? a[j].y : (kk == 2) ? a[j].z : a[j].w;
                acc[j][0] = fmaf(av, aw[0], acc[j][0]);
                acc[j][1] = fmaf(av, aw[1], acc[j][1]);
                acc[j][2] = fmaf(av, aw[2], acc[j][2]);
                acc[j][3] = fmaf(av, aw[3], acc[j][3]);
            }
        }
    }
#pragma unroll
    for (int j = 0; j < 4; ++j) {
        long long r = base + 4 * tr + j;
        if (r < N)
            *(float4*)(h2 + r * OUTC + 4 * tc) =
                make_float4(acc[j][0], acc[j][1], acc[j][2], acc[j][3]);
    }
}

// out = sum h2[rs_e]*dinv[rs_e]*dinv[n] + h2[n]*dinv^2 + b2   (wave = 1 node)
__global__ __launch_bounds__(256) void k_gather2(
    const int* __restrict__ start, const int* __restrict__ cnt,
    const float* __restrict__ dinv, const int* __restrict__ rs,
    const float* __restrict__ h2, const float* __restrict__ b2,
    float* __restrict__ out, int N) {
    int ln = threadIdx.x >> 6;
    int c  = threadIdx.x & 63;
    int n  = blockIdx.x * 4 + ln;
    if (n >= N) return;
    float dv = dinv[n];
    float acc = fmaf(h2[(size_t)n * OUTC + c], dv * dv, b2[c]);
    int s0 = start[n], k = cnt[n];
#pragma unroll 4
    for (int j = 0; j < k; ++j) {
        int r = rs[s0 + j];
        float nrm = dinv[r] * dv;
        acc = fmaf(h2[(size_t)r * OUTC + c], nrm, acc);
    }
    out[(size_t)n * OUTC + c] = acc;
}

extern "C" void kernel_launch(void* const* d_in, const int* in_sizes, int n_in,
                              void* d_out, int out_size, void* d_ws, size_t ws_size,
                              hipStream_t stream) {
    const float* x  = (const float*)d_in[0];
    const int*   ei = (const int*)d_in[1];
    const float* W1 = (const float*)d_in[2];
    const float* b1 = (const float*)d_in[3];
    const float* W2 = (const float*)d_in[4];
    const float* b2 = (const float*)d_in[5];
    float* out = (float*)d_out;

    const int N = in_sizes[0] / IN_CH;
    const int E = in_sizes[1] / 2;
    const int* row = ei;
    const int* col = ei + E;

    char* ws = (char*)d_ws;
    int*   cnt   = (int*)ws;                       // N
    int*   total = cnt + N;                        // 1  (cnt..total: N+1 ints, zeroed)
    int*   cur   = total + 64;                     // N  (written by k_alloc)
    int*   start = cur + N;                        // N
    float* dinv  = (float*)(start + N);            // N
    char*  p     = (char*)(dinv + N);
    p = (char*)(((uintptr_t)p + 255) & ~(uintptr_t)255);
    int*   rs    = (int*)p;                        // E ints (6.4 MB)
    float* aggx  = (float*)(rs + E);               // N*12
    float* out1  = aggx + (size_t)N * IN_CH;       // N*128
    float* h2    = out1 + (size_t)N * HID;         // N*64

    k_zero_i<<<(N + 1 + 255) / 256, 256, 0, stream>>>(cnt, N + 1);
    k_count<<<(E + 255) / 256, 256, 0, stream>>>(col, cnt, E);
    k_alloc<<<(N + 255) / 256, 256, 0, stream>>>(cnt, dinv, start, cur, total, N);
    k_fill<<<(E + 255) / 256, 256, 0, stream>>>(row, col, cur, rs, E);

    k_gather_x<<<(N + 15) / 16, 192, 0, stream>>>(start, cnt, dinv, rs, x, aggx, N);
    k_gemm1b<<<(N + 15) / 16, 256, 0, stream>>>(aggx, W1, b1, out1, N);
    k_gemm2<<<(N + 63) / 64, 256, 0, stream>>>(out1, W2, h2, N);
    k_gather2<<<(N + 3) / 4, 256, 0, stream>>>(start, cnt, dinv, rs, h2, b2, out, N);
}

// Round 6
// 354.344 us; speedup vs baseline: 1.0827x; 1.0827x over previous
//
#include <hip/hip_runtime.h>

// 2-layer GCN, CSR-gather formulation (no float atomics).
// A_norm·(x@W1) = (A_norm·x)@W1 -> layer-1 aggregation in 12-ch space.
// CSR payload = int2{row, norm} (norm precomputed; scattered-write cost is
// sector-bound, so the 8B payload is free vs 4B — measured r4 vs r5).
// Atomic-bound kernels batch 8 edges/thread for memory-level parallelism.

#define IN_CH 12
#define HID 128
#define OUTC 64
#define PADK 132  // A-tile row stride in floats for gemm2 (breaks pow2 bank stride)

__global__ void k_zero_i(int* __restrict__ p, int n) {
    int i = blockIdx.x * blockDim.x + threadIdx.x;
    if (i < n) p[i] = 0;
}

// 8 edges per thread: int4 loads, 8 independent atomics in flight
__global__ void k_count(const int* __restrict__ col, int* __restrict__ cnt, int E) {
    int base = (blockIdx.x * blockDim.x + threadIdx.x) * 8;
    if (base >= E) return;
    if (base + 8 <= E) {
        int4 c0 = *(const int4*)(col + base);
        int4 c1 = *(const int4*)(col + base + 4);
        atomicAdd(&cnt[c0.x], 1); atomicAdd(&cnt[c0.y], 1);
        atomicAdd(&cnt[c0.z], 1); atomicAdd(&cnt[c0.w], 1);
        atomicAdd(&cnt[c1.x], 1); atomicAdd(&cnt[c1.y], 1);
        atomicAdd(&cnt[c1.z], 1); atomicAdd(&cnt[c1.w], 1);
    } else {
        for (int e = base; e < E; ++e) atomicAdd(&cnt[col[e]], 1);
    }
}

// dinv[i]=rsqrt(cnt[i]+1); start[i]=exclusive running offset (cur stays zeroed)
__global__ __launch_bounds__(256) void k_alloc(
    const int* __restrict__ cnt, float* __restrict__ dinv,
    int* __restrict__ start, int* __restrict__ total, int N) {
    __shared__ int sdata[256];
    __shared__ int sbase;
    int i = blockIdx.x * 256 + threadIdx.x;
    int v = (i < N) ? cnt[i] : 0;
    if (i < N) dinv[i] = rsqrtf((float)v + 1.0f);
    sdata[threadIdx.x] = v;
    __syncthreads();
#pragma unroll
    for (int off = 1; off < 256; off <<= 1) {
        int t = (threadIdx.x >= off) ? sdata[threadIdx.x - off] : 0;
        __syncthreads();
        sdata[threadIdx.x] += t;
        __syncthreads();
    }
    if (threadIdx.x == 255) sbase = atomicAdd(total, sdata[255]);
    __syncthreads();
    if (i < N) start[i] = sbase + sdata[threadIdx.x] - v;  // exclusive scan
}

// edges[start[col]+cur[col]++] = {row, norm}; 8 edges/thread, atomics batched
__global__ void k_fill(const int* __restrict__ row, const int* __restrict__ col,
                       const float* __restrict__ dinv, const int* __restrict__ start,
                       int* __restrict__ cur, int2* __restrict__ edges, int E) {
    int base = (blockIdx.x * blockDim.x + threadIdx.x) * 8;
    if (base >= E) return;
    if (base + 8 <= E) {
        int4 r0 = *(const int4*)(row + base);
        int4 r1 = *(const int4*)(row + base + 4);
        int4 c0 = *(const int4*)(col + base);
        int4 c1 = *(const int4*)(col + base + 4);
        int rr[8] = {r0.x, r0.y, r0.z, r0.w, r1.x, r1.y, r1.z, r1.w};
        int cc[8] = {c0.x, c0.y, c0.z, c0.w, c1.x, c1.y, c1.z, c1.w};
        float nm[8];
        int p[8];
#pragma unroll
        for (int i = 0; i < 8; ++i) nm[i] = dinv[rr[i]] * dinv[cc[i]];
#pragma unroll
        for (int i = 0; i < 8; ++i) p[i] = start[cc[i]] + atomicAdd(&cur[cc[i]], 1);
#pragma unroll
        for (int i = 0; i < 8; ++i) edges[p[i]] = make_int2(rr[i], __float_as_int(nm[i]));
    } else {
        for (int e = base; e < E; ++e) {
            int r = row[e], c = col[e];
            int p = start[c] + atomicAdd(&cur[c], 1);
            edges[p] = make_int2(r, __float_as_int(dinv[r] * dinv[c]));
        }
    }
}

// Fused layer 1: aggx = A_norm·x (in registers/LDS) then out1 = relu(aggx@W1 + b1)
// block = 256 threads; gather phase: 16 nodes x 16 lanes (12 active);
// gemm phase: 128 ch x 2 halves, 8 nodes each.
__global__ __launch_bounds__(256) void k_l1(
    const int* __restrict__ start, const int* __restrict__ cnt,
    const float* __restrict__ dinv, const int2* __restrict__ edges,
    const float* __restrict__ x, const float* __restrict__ W1,
    const float* __restrict__ b1, float* __restrict__ out1, int N) {
    __shared__ float w1s[IN_CH * HID];  // 6 KiB
    __shared__ float axs[16][IN_CH];
    for (int i = threadIdx.x; i < IN_CH * HID; i += 256) w1s[i] = W1[i];
    int g = threadIdx.x >> 4;   // node group 0..15
    int c = threadIdx.x & 15;   // lane in group; active c < 12
    long long base = (long long)blockIdx.x * 16;
    long long n = base + g;
    if (c < IN_CH) {
        float acc = 0.0f;
        if (n < N) {
            float dv = dinv[n];
            acc = x[n * IN_CH + c] * dv * dv;
            int s0 = start[n], k = cnt[n];
            int j = 0;
            for (; j + 4 <= k; j += 4) {
                int2 e0 = edges[s0 + j + 0], e1 = edges[s0 + j + 1];
                int2 e2 = edges[s0 + j + 2], e3 = edges[s0 + j + 3];
                float v0 = x[(size_t)e0.x * IN_CH + c];
                float v1 = x[(size_t)e1.x * IN_CH + c];
                float v2 = x[(size_t)e2.x * IN_CH + c];
                float v3 = x[(size_t)e3.x * IN_CH + c];
                acc = fmaf(v0, __int_as_float(e0.y), acc);
                acc = fmaf(v1, __int_as_float(e1.y), acc);
                acc = fmaf(v2, __int_as_float(e2.y), acc);
                acc = fmaf(v3, __int_as_float(e3.y), acc);
            }
            for (; j < k; ++j) {
                int2 e = edges[s0 + j];
                acc = fmaf(x[(size_t)e.x * IN_CH + c], __int_as_float(e.y), acc);
            }
        }
        axs[g][c] = acc;
    }
    __syncthreads();
    int c2   = threadIdx.x & 127;
    int half = threadIdx.x >> 7;
    float bb = b1[c2];
    float acc2[8];
#pragma unroll
    for (int j = 0; j < 8; ++j) acc2[j] = bb;
#pragma unroll
    for (int k = 0; k < IN_CH; ++k) {
        float w = w1s[k * HID + c2];
#pragma unroll
        for (int j = 0; j < 8; ++j)
            acc2[j] = fmaf(axs[half * 8 + j][k], w, acc2[j]);
    }
#pragma unroll
    for (int j = 0; j < 8; ++j) {
        long long nn = base + half * 8 + j;
        if (nn < N) out1[nn * HID + c2] = fmaxf(acc2[j], 0.0f);
    }
}

// h2 = out1 @ W2 : LDS-tiled GEMM, 64x64 tile, 4x4 register tile per thread
__global__ __launch_bounds__(256) void k_gemm2(
    const float* __restrict__ out1, const float* __restrict__ W2,
    float* __restrict__ h2, int N) {
    __shared__ float as[64 * PADK];   // 33.8 KiB
    __shared__ float ws[HID * OUTC];  // 32 KiB
    for (int i = threadIdx.x; i < (HID * OUTC) / 4; i += 256)
        ((float4*)ws)[i] = ((const float4*)W2)[i];
    long long base = (long long)blockIdx.x * 64;
    for (int i = threadIdx.x; i < 2048; i += 256) {
        int r = i >> 5, kq = i & 31;
        long long rr = base + r; if (rr >= N) rr = N - 1;
        float4 v = ((const float4*)(out1 + rr * HID))[kq];
        *(float4*)(as + r * PADK + 4 * kq) = v;
    }
    __syncthreads();
    int tc = threadIdx.x & 15;
    int tr = threadIdx.x >> 4;
    float acc[4][4] = {};
    const float* ar = as + 4 * tr * PADK;
#pragma unroll 8
    for (int k = 0; k < HID; k += 4) {
        float4 a[4], w[4];
#pragma unroll
        for (int j = 0; j < 4; ++j) a[j] = *(const float4*)(ar + j * PADK + k);
#pragma unroll
        for (int kk = 0; kk < 4; ++kk) w[kk] = *(const float4*)(ws + (k + kk) * OUTC + 4 * tc);
#pragma unroll
        for (int kk = 0; kk < 4; ++kk) {
            float aw[4] = {w[kk].x, w[kk].y, w[kk].z, w[kk].w};
#pragma unroll
            for (int j = 0; j < 4; ++j) {
                float av = (kk == 0) ? a[j].x : (kk == 1) ? a[j].y : (kk == 2) ? a[j].z : a[j].w;
                acc[j][0] = fmaf(av, aw[0], acc[j][0]);
                acc[j][1] = fmaf(av, aw[1], acc[j][1]);
                acc[j][2] = fmaf(av, aw[2], acc[j][2]);
                acc[j][3] = fmaf(av, aw[3], acc[j][3]);
            }
        }
    }
#pragma unroll
    for (int j = 0; j < 4; ++j) {
        long long r = base + 4 * tr + j;
        if (r < N)
            *(float4*)(h2 + r * OUTC + 4 * tc) =
                make_float4(acc[j][0], acc[j][1], acc[j][2], acc[j][3]);
    }
}

// out = sum h2[row_e]*norm_e + h2[n]*dinv^2 + b2; wave = 1 node, lane = channel;
// 4-deep edge pipeline (4 independent row loads in flight).
__global__ __launch_bounds__(256) void k_gather2(
    const int* __restrict__ start, const int* __restrict__ cnt,
    const float* __restrict__ dinv, const int2* __restrict__ edges,
    const float* __restrict__ h2, const float* __restrict__ b2,
    float* __restrict__ out, int N) {
    int ln = threadIdx.x >> 6;
    int c  = threadIdx.x & 63;
    int n  = blockIdx.x * 4 + ln;
    if (n >= N) return;
    float dv = dinv[n];
    float acc = fmaf(h2[(size_t)n * OUTC + c], dv * dv, b2[c]);
    int s0 = start[n], k = cnt[n];
    int j = 0;
    for (; j + 4 <= k; j += 4) {
        int2 e0 = edges[s0 + j + 0], e1 = edges[s0 + j + 1];
        int2 e2 = edges[s0 + j + 2], e3 = edges[s0 + j + 3];
        float v0 = h2[(size_t)e0.x * OUTC + c];
        float v1 = h2[(size_t)e1.x * OUTC + c];
        float v2 = h2[(size_t)e2.x * OUTC + c];
        float v3 = h2[(size_t)e3.x * OUTC + c];
        acc = fmaf(v0, __int_as_float(e0.y), acc);
        acc = fmaf(v1, __int_as_float(e1.y), acc);
        acc = fmaf(v2, __int_as_float(e2.y), acc);
        acc = fmaf(v3, __int_as_float(e3.y), acc);
    }
    for (; j < k; ++j) {
        int2 e = edges[s0 + j];
        acc = fmaf(h2[(size_t)e.x * OUTC + c], __int_as_float(e.y), acc);
    }
    out[(size_t)n * OUTC + c] = acc;
}

extern "C" void kernel_launch(void* const* d_in, const int* in_sizes, int n_in,
                              void* d_out, int out_size, void* d_ws, size_t ws_size,
                              hipStream_t stream) {
    const float* x  = (const float*)d_in[0];
    const int*   ei = (const int*)d_in[1];
    const float* W1 = (const float*)d_in[2];
    const float* b1 = (const float*)d_in[3];
    const float* W2 = (const float*)d_in[4];
    const float* b2 = (const float*)d_in[5];
    float* out = (float*)d_out;

    const int N = in_sizes[0] / IN_CH;
    const int E = in_sizes[1] / 2;
    const int* row = ei;
    const int* col = ei + E;

    char* ws = (char*)d_ws;
    int*   cnt   = (int*)ws;                       // N
    int*   cur   = cnt + N;                        // N
    int*   total = cur + N;                        // 1 (cnt..total: 2N+1 ints zeroed)
    int*   start = total + 64;                     // N
    float* dinv  = (float*)(start + N + 64);       // N
    char*  p     = (char*)(dinv + N);
    p = (char*)(((uintptr_t)p + 255) & ~(uintptr_t)255);
    int2*  edges = (int2*)p;                       // E int2 (12.8 MB)
    float* out1  = (float*)(edges + E);            // N*128
    float* h2    = out1 + (size_t)N * HID;         // N*64

    const int EB = (E + 8 * 256 - 1) / (8 * 256);  // blocks for 8-edges/thread kernels

    k_zero_i<<<(2 * N + 1 + 255) / 256, 256, 0, stream>>>(cnt, 2 * N + 1);
    k_count<<<EB, 256, 0, stream>>>(col, cnt, E);
    k_alloc<<<(N + 255) / 256, 256, 0, stream>>>(cnt, dinv, start, total, N);
    k_fill<<<EB, 256, 0, stream>>>(row, col, dinv, start, cur, edges, E);

    k_l1<<<(N + 15) / 16, 256, 0, stream>>>(start, cnt, dinv, edges, x, W1, b1, out1, N);
    k_gemm2<<<(N + 63) / 64, 256, 0, stream>>>(out1, W2, h2, N);
    k_gather2<<<(N + 3) / 4, 256, 0, stream>>>(start, cnt, dinv, edges, h2, b2, out, N);
}

// Round 7
// 323.594 us; speedup vs baseline: 1.1856x; 1.0950x over previous
//
#include <hip/hip_runtime.h>

// 2-layer GCN, CSR-gather formulation (no float atomics).
// A_norm·(x@W1) = (A_norm·x)@W1 -> layer-1 aggregation in 12-ch space.
// CSR payload = int2{row, norm}. k_fill is destination-range partitioned
// (8 ranges, blockIdx&7) so each range's CSR window is L2-resident on one XCD:
// scattered writes coalesce to full sectors in L2 instead of 64B/edge to HBM.

#define IN_CH 12
#define HID 128
#define OUTC 64
#define PADK 132  // A-tile row stride in floats for gemm2 (breaks pow2 bank stride)

__global__ void k_zero_i(int* __restrict__ p, int n) {
    int i = blockIdx.x * blockDim.x + threadIdx.x;
    if (i < n) p[i] = 0;
}

__global__ void k_count(const int* __restrict__ col, int* __restrict__ cnt, int E) {
    int e = blockIdx.x * blockDim.x + threadIdx.x;
    if (e < E) atomicAdd(&cnt[col[e]], 1);
}

// dinv[i]=rsqrt(cnt[i]+1); start[i]=exclusive running offset (cur stays zeroed)
__global__ __launch_bounds__(256) void k_alloc(
    const int* __restrict__ cnt, float* __restrict__ dinv,
    int* __restrict__ start, int* __restrict__ total, int N) {
    __shared__ int sdata[256];
    __shared__ int sbase;
    int i = blockIdx.x * 256 + threadIdx.x;
    int v = (i < N) ? cnt[i] : 0;
    if (i < N) dinv[i] = rsqrtf((float)v + 1.0f);
    sdata[threadIdx.x] = v;
    __syncthreads();
#pragma unroll
    for (int off = 1; off < 256; off <<= 1) {
        int t = (threadIdx.x >= off) ? sdata[threadIdx.x - off] : 0;
        __syncthreads();
        sdata[threadIdx.x] += t;
        __syncthreads();
    }
    if (threadIdx.x == 255) sbase = atomicAdd(total, sdata[255]);
    __syncthreads();
    if (i < N) start[i] = sbase + sdata[threadIdx.x] - v;  // exclusive scan
}

// Destination-range-partitioned fill: block b handles range (b&7).
// Each range's 1.6MB CSR window stays L2-resident on (mostly) one XCD.
__global__ void k_fill(const int* __restrict__ row, const int* __restrict__ col,
                       const float* __restrict__ dinv, const int* __restrict__ start,
                       int* __restrict__ cur, int2* __restrict__ edges,
                       int E, int per) {
    int part  = blockIdx.x & 7;
    int chunk = blockIdx.x >> 3;
    int e = chunk * 256 + threadIdx.x;
    if (e >= E) return;
    int c = col[e];
    int lo = part * per;
    if (c < lo || c >= lo + per) return;
    int r = row[e];
    int p = start[c] + atomicAdd(&cur[c], 1);
    edges[p] = make_int2(r, __float_as_int(dinv[r] * dinv[c]));
}

// aggx[n] = sum_{e->n} x[row_e]*norm_e + x[n]*dinv^2   (12 channels)
// block = 192 threads = 16 nodes x 12 lanes
__global__ __launch_bounds__(192) void k_gather_x(
    const int* __restrict__ start, const int* __restrict__ cnt,
    const float* __restrict__ dinv, const int2* __restrict__ edges,
    const float* __restrict__ x, float* __restrict__ aggx, int N) {
    int ln = threadIdx.x / 12;
    int c  = threadIdx.x % 12;
    int n  = blockIdx.x * 16 + ln;
    if (n >= N) return;
    float dv = dinv[n];
    float acc = x[(size_t)n * IN_CH + c] * dv * dv;
    int s0 = start[n], k = cnt[n];
#pragma unroll 4
    for (int j = 0; j < k; ++j) {
        int2 e = edges[s0 + j];
        acc = fmaf(x[(size_t)e.x * IN_CH + c], __int_as_float(e.y), acc);
    }
    aggx[(size_t)n * IN_CH + c] = acc;
}

// out1 = relu(aggx @ W1 + b1)   (block = 256 threads, 16 nodes x 128 ch)
__global__ __launch_bounds__(256) void k_gemm1b(
    const float* __restrict__ aggx, const float* __restrict__ W1,
    const float* __restrict__ b1, float* __restrict__ out1, int N) {
    __shared__ float w1s[IN_CH * HID];  // 6 KiB
    __shared__ float axs[16][IN_CH];    // 768 B
    for (int i = threadIdx.x; i < IN_CH * HID; i += 256) w1s[i] = W1[i];
    long long base = (long long)blockIdx.x * 16;
    if (threadIdx.x < 16 * IN_CH) {
        int r = threadIdx.x / IN_CH, k = threadIdx.x % IN_CH;
        long long n = base + r;
        axs[r][k] = (n < N) ? aggx[n * IN_CH + k] : 0.0f;
    }
    __syncthreads();
    int c    = threadIdx.x & 127;
    int half = threadIdx.x >> 7;
    float bb = b1[c];
    float acc[8];
#pragma unroll
    for (int j = 0; j < 8; ++j) acc[j] = bb;
#pragma unroll
    for (int k = 0; k < IN_CH; ++k) {
        float w = w1s[k * HID + c];
#pragma unroll
        for (int j = 0; j < 8; ++j)
            acc[j] = fmaf(axs[half * 8 + j][k], w, acc[j]);
    }
#pragma unroll
    for (int j = 0; j < 8; ++j) {
        long long n = base + half * 8 + j;
        if (n < N) out1[n * HID + c] = fmaxf(acc[j], 0.0f);
    }
}

// h2 = out1 @ W2 : LDS-tiled GEMM, 64x64 tile, 4x4 register tile per thread
__global__ __launch_bounds__(256) void k_gemm2(
    const float* __restrict__ out1, const float* __restrict__ W2,
    float* __restrict__ h2, int N) {
    __shared__ float as[64 * PADK];   // 33.8 KiB
    __shared__ float ws[HID * OUTC];  // 32 KiB
    for (int i = threadIdx.x; i < (HID * OUTC) / 4; i += 256)
        ((float4*)ws)[i] = ((const float4*)W2)[i];
    long long base = (long long)blockIdx.x * 64;
    for (int i = threadIdx.x; i < 2048; i += 256) {
        int r = i >> 5, kq = i & 31;
        long long rr = base + r; if (rr >= N) rr = N - 1;
        float4 v = ((const float4*)(out1 + rr * HID))[kq];
        *(float4*)(as + r * PADK + 4 * kq) = v;
    }
    __syncthreads();
    int tc = threadIdx.x & 15;
    int tr = threadIdx.x >> 4;
    float acc[4][4] = {};
    const float* ar = as + 4 * tr * PADK;
#pragma unroll 8
    for (int k = 0; k < HID; k += 4) {
        float4 a[4], w[4];
#pragma unroll
        for (int j = 0; j < 4; ++j) a[j] = *(const float4*)(ar + j * PADK + k);
#pragma unroll
        for (int kk = 0; kk < 4; ++kk) w[kk] = *(const float4*)(ws + (k + kk) * OUTC + 4 * tc);
#pragma unroll
        for (int kk = 0; kk < 4; ++kk) {
            float aw[4] = {w[kk].x, w[kk].y, w[kk].z, w[kk].w};
#pragma unroll
            for (int j = 0; j < 4; ++j) {
                float av = (kk == 0) ? a[j].x : (kk == 1) ? a[j].y : (kk == 2) ? a[j].z : a[j].w;
                acc[j][0] = fmaf(av, aw[0], acc[j][0]);
                acc[j][1] = fmaf(av, aw[1], acc[j][1]);
                acc[j][2] = fmaf(av, aw[2], acc[j][2]);
                acc[j][3] = fmaf(av, aw[3], acc[j][3]);
            }
        }
    }
#pragma unroll
    for (int j = 0; j < 4; ++j) {
        long long r = base + 4 * tr + j;
        if (r < N)
            *(float4*)(h2 + r * OUTC + 4 * tc) =
                make_float4(acc[j][0], acc[j][1], acc[j][2], acc[j][3]);
    }
}

// out = sum h2[row_e]*norm_e + h2[n]*dinv^2 + b2   (wave = 1 node, lane = channel)
__global__ __launch_bounds__(256) void k_gather2(
    const int* __restrict__ start, const int* __restrict__ cnt,
    const float* __restrict__ dinv, const int2* __restrict__ edges,
    const float* __restrict__ h2, const float* __restrict__ b2,
    float* __restrict__ out, int N) {
    int ln = threadIdx.x >> 6;
    int c  = threadIdx.x & 63;
    int n  = blockIdx.x * 4 + ln;
    if (n >= N) return;
    float dv = dinv[n];
    float acc = fmaf(h2[(size_t)n * OUTC + c], dv * dv, b2[c]);
    int s0 = start[n], k = cnt[n];
#pragma unroll 4
    for (int j = 0; j < k; ++j) {
        int2 e = edges[s0 + j];
        acc = fmaf(h2[(size_t)e.x * OUTC + c], __int_as_float(e.y), acc);
    }
    out[(size_t)n * OUTC + c] = acc;
}

extern "C" void kernel_launch(void* const* d_in, const int* in_sizes, int n_in,
                              void* d_out, int out_size, void* d_ws, size_t ws_size,
                              hipStream_t stream) {
    const float* x  = (const float*)d_in[0];
    const int*   ei = (const int*)d_in[1];
    const float* W1 = (const float*)d_in[2];
    const float* b1 = (const float*)d_in[3];
    const float* W2 = (const float*)d_in[4];
    const float* b2 = (const float*)d_in[5];
    float* out = (float*)d_out;

    const int N = in_sizes[0] / IN_CH;
    const int E = in_sizes[1] / 2;
    const int* row = ei;
    const int* col = ei + E;

    char* ws = (char*)d_ws;
    int*   cnt   = (int*)ws;                       // N
    int*   cur   = cnt + N;                        // N
    int*   total = cur + N;                        // 1 (cnt..total: 2N+1 ints zeroed)
    int*   start = total + 64;                     // N
    float* dinv  = (float*)(start + N + 64);       // N
    char*  p     = (char*)(dinv + N);
    p = (char*)(((uintptr_t)p + 255) & ~(uintptr_t)255);
    int2*  edges = (int2*)p;                       // E int2 (12.8 MB)
    float* aggx  = (float*)(edges + E);            // N*12
    float* out1  = aggx + (size_t)N * IN_CH;       // N*128
    float* h2    = out1 + (size_t)N * HID;         // N*64

    const int per = (N + 7) / 8;                   // destination range size
    const int chunks = (E + 255) / 256;

    k_zero_i<<<(2 * N + 1 + 255) / 256, 256, 0, stream>>>(cnt, 2 * N + 1);
    k_count<<<chunks, 256, 0, stream>>>(col, cnt, E);
    k_alloc<<<(N + 255) / 256, 256, 0, stream>>>(cnt, dinv, start, total, N);
    k_fill<<<chunks * 8, 256, 0, stream>>>(row, col, dinv, start, cur, edges, E, per);

    k_gather_x<<<(N + 15) / 16, 192, 0, stream>>>(start, cnt, dinv, edges, x, aggx, N);
    k_gemm1b<<<(N + 15) / 16, 256, 0, stream>>>(aggx, W1, b1, out1, N);
    k_gemm2<<<(N + 63) / 64, 256, 0, stream>>>(out1, W2, h2, N);
    k_gather2<<<(N + 3) / 4, 256, 0, stream>>>(start, cnt, dinv, edges, h2, b2, out, N);
}